// Round 4
// baseline (426.593 us; speedup 1.0000x reference)
//
#include <hip/hip_runtime.h>

#define NB 8
#define NN 2048
#define NF 256

typedef __attribute__((ext_vector_type(8))) short bf16x8;
typedef __attribute__((ext_vector_type(4))) float f32x4;

__device__ __forceinline__ unsigned short f2bf(float x) {
  union { float f; unsigned int i; } c; c.f = x;
  unsigned int r = c.i + 0x7FFFu + ((c.i >> 16) & 1u);
  return (unsigned short)(r >> 16);
}
// round-half-up bf16 (1 add + 1 shift) — hot convert paths
__device__ __forceinline__ unsigned short f2bf_fast(float x) {
  union { float f; unsigned int i; } c; c.f = x;
  return (unsigned short)((c.i + 0x8000u) >> 16);
}
__device__ __forceinline__ bf16x8 cvt8(float4 c0, float4 c1) {
  union { bf16x8 v8; unsigned short us[8]; } cu;
  cu.us[0] = f2bf_fast(c0.x); cu.us[1] = f2bf_fast(c0.y);
  cu.us[2] = f2bf_fast(c0.z); cu.us[3] = f2bf_fast(c0.w);
  cu.us[4] = f2bf_fast(c1.x); cu.us[5] = f2bf_fast(c1.y);
  cu.us[6] = f2bf_fast(c1.z); cu.us[7] = f2bf_fast(c1.w);
  return cu.v8;
}

// ---------------------------------------------------------------------------
// k_prep: WT[f][k] = bf16(W[k][f]);  u = W @ a1, v = W @ a2  (fp32)
// ---------------------------------------------------------------------------
__global__ __launch_bounds__(256) void k_prep(
    const float* __restrict__ W, const float* __restrict__ a,
    unsigned short* __restrict__ WT, float* __restrict__ u, float* __restrict__ v) {
  int t = threadIdx.x;
  if (blockIdx.x < 256) {
    int k = blockIdx.x;
    WT[t * 256 + k] = f2bf(W[k * 256 + t]);
  } else {
    float su = 0.f, sv = 0.f;
    for (int o = 0; o < 256; ++o) {
      float w = W[t * 256 + o];
      su += w * a[o];
      sv += w * a[256 + o];
    }
    u[t] = su; v[t] = sv;
  }
}

// ---------------------------------------------------------------------------
// k_wht: WhT[b][f][i] = sum_k W[k][f] * h[b][i][k]
// grid 512: b(8) x [fblk(4,64f) x iblk(16,128i)]; 4 waves (2f x 2i), wave 32f x 64i
// ---------------------------------------------------------------------------
__global__ __launch_bounds__(256) void k_wht(
    const float* __restrict__ h, const unsigned short* __restrict__ WTr,
    unsigned short* __restrict__ WhT) {
  int bx = blockIdx.x;
  int b = bx >> 6;
  int t = bx & 63;
  int fBlk = (t >> 4) * 64;
  int iBlk = (t & 15) * 128;
  int wave = threadIdx.x >> 6, lane = threadIdx.x & 63;
  int fW = fBlk + (wave >> 1) * 32;
  int iW = iBlk + (wave & 1) * 64;
  int l15 = lane & 15, q8 = (lane >> 4) * 8;
  const float* hB = h + (size_t)b * NN * NF;

  f32x4 acc[2][4];
#pragma unroll
  for (int mt = 0; mt < 2; ++mt)
#pragma unroll
    for (int nt = 0; nt < 4; ++nt)
      acc[mt][nt] = (f32x4){0.f, 0.f, 0.f, 0.f};

  for (int k0 = 0; k0 < NF; k0 += 32) {
    int kk = k0 + q8;
    bf16x8 af[2], bfr[4];
#pragma unroll
    for (int mt = 0; mt < 2; ++mt) {
      int f = fW + mt * 16 + l15;
      af[mt] = *(const bf16x8*)(WTr + f * 256 + kk);
    }
#pragma unroll
    for (int nt = 0; nt < 4; ++nt) {
      int i = iW + nt * 16 + l15;
      const float* p = hB + (size_t)i * NF + kk;
      bfr[nt] = cvt8(*(const float4*)p, *(const float4*)(p + 4));
    }
#pragma unroll
    for (int mt = 0; mt < 2; ++mt)
#pragma unroll
      for (int nt = 0; nt < 4; ++nt)
        acc[mt][nt] = __builtin_amdgcn_mfma_f32_16x16x32_bf16(af[mt], bfr[nt], acc[mt][nt], 0, 0, 0);
  }

  unsigned short* WhTb = WhT + (size_t)b * NF * NN;
  int q4 = (lane >> 4) * 4;
#pragma unroll
  for (int mt = 0; mt < 2; ++mt)
#pragma unroll
    for (int nt = 0; nt < 4; ++nt)
#pragma unroll
      for (int r = 0; r < 4; ++r) {
        int f = fW + mt * 16 + q4 + r;
        int i = iW + nt * 16 + l15;
        WhTb[(size_t)f * NN + i] = f2bf(acc[mt][nt][r]);
      }
}

// ---------------------------------------------------------------------------
// k_proj: Wh1[row] = h[row,:] . u ; Wh2[row] = h[row,:] . v  (wave per row, fp32)
// ---------------------------------------------------------------------------
__global__ __launch_bounds__(256) void k_proj(
    const float* __restrict__ h, const float* __restrict__ u,
    const float* __restrict__ v, float* __restrict__ Wh1, float* __restrict__ Wh2) {
  int row = blockIdx.x * 4 + (threadIdx.x >> 6);
  int lane = threadIdx.x & 63;
  float4 hv = *(const float4*)(h + (size_t)row * NF + lane * 4);
  const float* up = u + lane * 4;
  const float* vp = v + lane * 4;
  float su = hv.x * up[0] + hv.y * up[1] + hv.z * up[2] + hv.w * up[3];
  float sv = hv.x * vp[0] + hv.y * vp[1] + hv.z * vp[2] + hv.w * vp[3];
#pragma unroll
  for (int off = 32; off >= 1; off >>= 1) {
    su += __shfl_xor(su, off);
    sv += __shfl_xor(sv, off);
  }
  if (lane == 0) { Wh1[row] = su; Wh2[row] = sv; }
}

// ---------------------------------------------------------------------------
// k_soft: pure streaming masked-softmax, one wave per row (64 lanes x 32 elems).
// No LDS, 256-thread blocks (4 rows/block) -> no residency cap; 16 loads in
// flight per wave. Writes fp32 att only. Split from the old fused kernel to
// isolate phase timing and give each phase its ideal launch config.
// grid 4096: rows 0..16383.
// ---------------------------------------------------------------------------
__global__ __launch_bounds__(256) void k_soft(
    const int* __restrict__ adj, const float* __restrict__ Wh1,
    const float* __restrict__ Wh2, float* __restrict__ att) {
  const float NEGBIG = -9.0e15f;
  int row = blockIdx.x * 4 + (threadIdx.x >> 6);  // global row 0..16383
  int lane = threadIdx.x & 63;
  int b = row >> 11;
  const float* w2 = Wh2 + (b << 11);
  const int* arow = adj + (size_t)row * NN;
  float w1 = Wh1[row];

  float x[32];
#pragma unroll
  for (int c = 0; c < 8; ++c) {
    int j = c * 256 + lane * 4;
    int4 av = *(const int4*)(arow + j);
    float4 pv = *(const float4*)(w2 + j);
    float t;
    t = w1 + pv.x; t = t >= 0.f ? t : 0.2f * t; x[c*4+0] = (av.x > 0) ? t : NEGBIG;
    t = w1 + pv.y; t = t >= 0.f ? t : 0.2f * t; x[c*4+1] = (av.y > 0) ? t : NEGBIG;
    t = w1 + pv.z; t = t >= 0.f ? t : 0.2f * t; x[c*4+2] = (av.z > 0) ? t : NEGBIG;
    t = w1 + pv.w; t = t >= 0.f ? t : 0.2f * t; x[c*4+3] = (av.w > 0) ? t : NEGBIG;
  }

  float m = x[0];
#pragma unroll
  for (int k = 1; k < 32; ++k) m = fmaxf(m, x[k]);
#pragma unroll
  for (int off = 32; off >= 1; off >>= 1) m = fmaxf(m, __shfl_xor(m, off));
  float sum = 0.f;
#pragma unroll
  for (int k = 0; k < 32; ++k) { x[k] = __expf(x[k] - m); sum += x[k]; }
#pragma unroll
  for (int off = 32; off >= 1; off >>= 1) sum += __shfl_xor(sum, off);
  float iv = 1.0f / sum;

  float* orow = att + (size_t)row * NN;
#pragma unroll
  for (int c = 0; c < 8; ++c) {
    int j = c * 256 + lane * 4;
    *(float4*)(orow + j) = make_float4(x[c*4+0] * iv, x[c*4+1] * iv,
                                       x[c*4+2] * iv, x[c*4+3] * iv);
  }
}

// ---------------------------------------------------------------------------
// k_pv: h_prime = att @ Wh, out = h + elu(h_prime).
// Stage 1: 16-row A-tile read from fp32 att (L3-hot, just written by k_soft),
//          cvt -> bf16 into XOR-swizzled LDS (identical layout to old fused
//          kernel: elem p of row r at satt[r][((p&~7)^ (r*8)) + (p&7)]).
// Stage 2: unchanged MFMA loop — wave owns a 32-wide f-stripe; A from LDS
//          ds_read_b128 (swizzled, conflict-free), B = WhT[b][f][j] 16B frags
//          (L2-resident); fused out = h + elu.
// grid 1024: b(8) x itile(128,16i); 512 thr / 8 waves; LDS 64 KB.
// ---------------------------------------------------------------------------
__global__ __launch_bounds__(512, 4) void k_pv(
    const float* __restrict__ attf, const unsigned short* __restrict__ WhT,
    const float* __restrict__ h, float* __restrict__ out) {
  __shared__ __align__(16) unsigned short satt[16 * 2048];  // 64 KB
  int bx = blockIdx.x;
  int b = bx >> 7;
  int i0 = (bx & 127) * 16;
  int tid = threadIdx.x;

  // ---- stage A-tile: 16 rows x 2048 fp32 -> bf16 swizzled LDS ----
  {
    int r = tid >> 5;                 // 0..15 (32 threads per row)
    int m0 = (tid & 31) * 8;          // 8 elems per thread per chunk
    const float* arow = attf + ((size_t)(b * NN + i0 + r)) * NN;
    unsigned short* srow = satt + r * 2048;
    int swz = r * 8;
#pragma unroll
    for (int c = 0; c < 8; ++c) {
      int j = c * 256 + m0;           // 8-aligned
      float4 p0 = *(const float4*)(arow + j);
      float4 p1 = *(const float4*)(arow + j + 4);
      *(bf16x8*)(srow + (j ^ swz)) = cvt8(p0, p1);
    }
  }
  __syncthreads();

  // ---- GEMM 16i x 256f x 2048j + fused epilogue ----
  int wave = tid >> 6, lane = tid & 63;
  int fW = wave * 32;
  int l15 = lane & 15, q8 = (lane >> 4) * 8;
  const unsigned short* WTb = WhT + (size_t)b * NF * NN;
  const unsigned short* aRow = satt + l15 * 2048;
  int swzA = l15 * 8;

  f32x4 acc[2];
#pragma unroll
  for (int nt = 0; nt < 2; ++nt) acc[nt] = (f32x4){0.f, 0.f, 0.f, 0.f};

  for (int kk = 0; kk < NN; kk += 32) {
    bf16x8 afr = *(const bf16x8*)(aRow + (((kk + q8) ^ swzA)));
    bf16x8 bfr[2];
#pragma unroll
    for (int nt = 0; nt < 2; ++nt) {
      int f = fW + nt * 16 + l15;
      bfr[nt] = *(const bf16x8*)(WTb + (size_t)f * NN + kk + q8);
    }
#pragma unroll
    for (int nt = 0; nt < 2; ++nt)
      acc[nt] = __builtin_amdgcn_mfma_f32_16x16x32_bf16(afr, bfr[nt], acc[nt], 0, 0, 0);
  }

  int q4 = (lane >> 4) * 4;
#pragma unroll
  for (int nt = 0; nt < 2; ++nt)
#pragma unroll
    for (int r = 0; r < 4; ++r) {
      int i = i0 + q4 + r;
      int f = fW + nt * 16 + l15;
      size_t idx = ((size_t)(b * NN + i)) * NF + f;
      float hp = acc[nt][r];
      float el = hp > 0.f ? hp : expm1f(hp);
      out[idx] = h[idx] + el;
    }
}

// ---------------------------------------------------------------------------
extern "C" void kernel_launch(void* const* d_in, const int* in_sizes, int n_in,
                              void* d_out, int out_size, void* d_ws, size_t ws_size,
                              hipStream_t stream) {
  // identify inputs by element count (all four are distinct)
  const float* h = nullptr; const int* adj = nullptr;
  const float* W = nullptr; const float* a = nullptr;
  for (int i = 0; i < n_in; ++i) {
    int s = in_sizes[i];
    if (s == NB * NN * NF) h = (const float*)d_in[i];
    else if (s == NB * NN * NN) adj = (const int*)d_in[i];
    else if (s == NF * NF) W = (const float*)d_in[i];
    else if (s == 2 * NF) a = (const float*)d_in[i];
  }

  float* out = (float*)d_out;                              // [8,2048,256] fp32
  float* att = out + (size_t)NB * NN * NF;                 // [8,2048,2048] fp32

  // ws footprint ~8.26 MB (proven safe)
  char* ws = (char*)d_ws;
  unsigned short* WhT = (unsigned short*)ws;               // 8 MB [8][256][2048] bf16
  unsigned short* WTr = (unsigned short*)(ws + 8388608);   // 128 KB [256][256] bf16
  float* u   = (float*)(ws + 8388608 + 131072);            // 1 KB
  float* v   = u + 256;                                    // 1 KB
  float* Wh1 = v + 256;                                    // 64 KB
  float* Wh2 = Wh1 + NB * NN;                              // 64 KB

  k_prep<<<257, 256, 0, stream>>>(W, a, WTr, u, v);
  k_wht<<<512, 256, 0, stream>>>(h, WTr, WhT);
  k_proj<<<NB * NN / 4, 256, 0, stream>>>(h, u, v, Wh1, Wh2);
  k_soft<<<NB * NN / 4, 256, 0, stream>>>(adj, Wh1, Wh2, att);
  k_pv<<<NB * 128, 512, 0, stream>>>(att, WhT, h, out);
}

// Round 5
// 421.516 us; speedup vs baseline: 1.0120x; 1.0120x over previous
//
#include <hip/hip_runtime.h>

#define NB 8
#define NN 2048
#define NF 256

typedef __attribute__((ext_vector_type(8))) short bf16x8;
typedef __attribute__((ext_vector_type(4))) float f32x4;

__device__ __forceinline__ unsigned short f2bf(float x) {
  union { float f; unsigned int i; } c; c.f = x;
  unsigned int r = c.i + 0x7FFFu + ((c.i >> 16) & 1u);
  return (unsigned short)(r >> 16);
}
// round-half-up bf16 (1 add + 1 shift) — hot convert paths
__device__ __forceinline__ unsigned short f2bf_fast(float x) {
  union { float f; unsigned int i; } c; c.f = x;
  return (unsigned short)((c.i + 0x8000u) >> 16);
}
__device__ __forceinline__ bf16x8 cvt8(float4 c0, float4 c1) {
  union { bf16x8 v8; unsigned short us[8]; } cu;
  cu.us[0] = f2bf_fast(c0.x); cu.us[1] = f2bf_fast(c0.y);
  cu.us[2] = f2bf_fast(c0.z); cu.us[3] = f2bf_fast(c0.w);
  cu.us[4] = f2bf_fast(c1.x); cu.us[5] = f2bf_fast(c1.y);
  cu.us[6] = f2bf_fast(c1.z); cu.us[7] = f2bf_fast(c1.w);
  return cu.v8;
}

// ---------------------------------------------------------------------------
// k_prep: WT[f][k] = bf16(W[k][f]);  u = W @ a1, v = W @ a2  (fp32)
// ---------------------------------------------------------------------------
__global__ __launch_bounds__(256) void k_prep(
    const float* __restrict__ W, const float* __restrict__ a,
    unsigned short* __restrict__ WT, float* __restrict__ u, float* __restrict__ v) {
  int t = threadIdx.x;
  if (blockIdx.x < 256) {
    int k = blockIdx.x;
    WT[t * 256 + k] = f2bf(W[k * 256 + t]);
  } else {
    float su = 0.f, sv = 0.f;
    for (int o = 0; o < 256; ++o) {
      float w = W[t * 256 + o];
      su += w * a[o];
      sv += w * a[256 + o];
    }
    u[t] = su; v[t] = sv;
  }
}

// ---------------------------------------------------------------------------
// k_wht: WhT[b][f][i] = sum_k W[k][f] * h[b][i][k]
// grid 512: b(8) x [fblk(4,64f) x iblk(16,128i)]; 4 waves (2f x 2i), wave 32f x 64i
// ---------------------------------------------------------------------------
__global__ __launch_bounds__(256) void k_wht(
    const float* __restrict__ h, const unsigned short* __restrict__ WTr,
    unsigned short* __restrict__ WhT) {
  int bx = blockIdx.x;
  int b = bx >> 6;
  int t = bx & 63;
  int fBlk = (t >> 4) * 64;
  int iBlk = (t & 15) * 128;
  int wave = threadIdx.x >> 6, lane = threadIdx.x & 63;
  int fW = fBlk + (wave >> 1) * 32;
  int iW = iBlk + (wave & 1) * 64;
  int l15 = lane & 15, q8 = (lane >> 4) * 8;
  const float* hB = h + (size_t)b * NN * NF;

  f32x4 acc[2][4];
#pragma unroll
  for (int mt = 0; mt < 2; ++mt)
#pragma unroll
    for (int nt = 0; nt < 4; ++nt)
      acc[mt][nt] = (f32x4){0.f, 0.f, 0.f, 0.f};

  for (int k0 = 0; k0 < NF; k0 += 32) {
    int kk = k0 + q8;
    bf16x8 af[2], bfr[4];
#pragma unroll
    for (int mt = 0; mt < 2; ++mt) {
      int f = fW + mt * 16 + l15;
      af[mt] = *(const bf16x8*)(WTr + f * 256 + kk);
    }
#pragma unroll
    for (int nt = 0; nt < 4; ++nt) {
      int i = iW + nt * 16 + l15;
      const float* p = hB + (size_t)i * NF + kk;
      bfr[nt] = cvt8(*(const float4*)p, *(const float4*)(p + 4));
    }
#pragma unroll
    for (int mt = 0; mt < 2; ++mt)
#pragma unroll
      for (int nt = 0; nt < 4; ++nt)
        acc[mt][nt] = __builtin_amdgcn_mfma_f32_16x16x32_bf16(af[mt], bfr[nt], acc[mt][nt], 0, 0, 0);
  }

  unsigned short* WhTb = WhT + (size_t)b * NF * NN;
  int q4 = (lane >> 4) * 4;
#pragma unroll
  for (int mt = 0; mt < 2; ++mt)
#pragma unroll
    for (int nt = 0; nt < 4; ++nt)
#pragma unroll
      for (int r = 0; r < 4; ++r) {
        int f = fW + mt * 16 + q4 + r;
        int i = iW + nt * 16 + l15;
        WhTb[(size_t)f * NN + i] = f2bf(acc[mt][nt][r]);
      }
}

// ---------------------------------------------------------------------------
// k_proj: Wh1[row] = h[row,:] . u ; Wh2[row] = h[row,:] . v  (wave per row, fp32)
// ---------------------------------------------------------------------------
__global__ __launch_bounds__(256) void k_proj(
    const float* __restrict__ h, const float* __restrict__ u,
    const float* __restrict__ v, float* __restrict__ Wh1, float* __restrict__ Wh2) {
  int row = blockIdx.x * 4 + (threadIdx.x >> 6);
  int lane = threadIdx.x & 63;
  float4 hv = *(const float4*)(h + (size_t)row * NF + lane * 4);
  const float* up = u + lane * 4;
  const float* vp = v + lane * 4;
  float su = hv.x * up[0] + hv.y * up[1] + hv.z * up[2] + hv.w * up[3];
  float sv = hv.x * vp[0] + hv.y * vp[1] + hv.z * vp[2] + hv.w * vp[3];
#pragma unroll
  for (int off = 32; off >= 1; off >>= 1) {
    su += __shfl_xor(su, off);
    sv += __shfl_xor(sv, off);
  }
  if (lane == 0) { Wh1[row] = su; Wh2[row] = sv; }
}

// ---------------------------------------------------------------------------
// k_soft: pure streaming masked-softmax, one wave per row (64 lanes x 32 elems).
// No LDS, 256-thread blocks (4 rows/block). ~68 us, near streaming roofline
// (268 MB adj+att at ~3.9 TB/s). grid 4096: rows 0..16383.
// ---------------------------------------------------------------------------
__global__ __launch_bounds__(256) void k_soft(
    const int* __restrict__ adj, const float* __restrict__ Wh1,
    const float* __restrict__ Wh2, float* __restrict__ att) {
  const float NEGBIG = -9.0e15f;
  int row = blockIdx.x * 4 + (threadIdx.x >> 6);  // global row 0..16383
  int lane = threadIdx.x & 63;
  int b = row >> 11;
  const float* w2 = Wh2 + (b << 11);
  const int* arow = adj + (size_t)row * NN;
  float w1 = Wh1[row];

  float x[32];
#pragma unroll
  for (int c = 0; c < 8; ++c) {
    int j = c * 256 + lane * 4;
    int4 av = *(const int4*)(arow + j);
    float4 pv = *(const float4*)(w2 + j);
    float t;
    t = w1 + pv.x; t = t >= 0.f ? t : 0.2f * t; x[c*4+0] = (av.x > 0) ? t : NEGBIG;
    t = w1 + pv.y; t = t >= 0.f ? t : 0.2f * t; x[c*4+1] = (av.y > 0) ? t : NEGBIG;
    t = w1 + pv.z; t = t >= 0.f ? t : 0.2f * t; x[c*4+2] = (av.z > 0) ? t : NEGBIG;
    t = w1 + pv.w; t = t >= 0.f ? t : 0.2f * t; x[c*4+3] = (av.w > 0) ? t : NEGBIG;
  }

  float m = x[0];
#pragma unroll
  for (int k = 1; k < 32; ++k) m = fmaxf(m, x[k]);
#pragma unroll
  for (int off = 32; off >= 1; off >>= 1) m = fmaxf(m, __shfl_xor(m, off));
  float sum = 0.f;
#pragma unroll
  for (int k = 0; k < 32; ++k) { x[k] = __expf(x[k] - m); sum += x[k]; }
#pragma unroll
  for (int off = 32; off >= 1; off >>= 1) sum += __shfl_xor(sum, off);
  float iv = 1.0f / sum;

  float* orow = att + (size_t)row * NN;
#pragma unroll
  for (int c = 0; c < 8; ++c) {
    int j = c * 256 + lane * 4;
    *(float4*)(orow + j) = make_float4(x[c*4+0] * iv, x[c*4+1] * iv,
                                       x[c*4+2] * iv, x[c*4+3] * iv);
  }
}

// ---------------------------------------------------------------------------
// k_pv: h_prime = att @ Wh, out = h + elu(h_prime).
// R5: (1) 4-stage rotating register prefetch for B + 1-stage LDS prefetch for A
//     — old loop loaded B and MFMA'd it immediately, exposing ~L2-miss/L3
//     latency every 32-wide K-step (counters: 144 us with NOTHING busy:
//     HBM 11%, Mfma 4.6%, VALU 5.8%). Load->use distance now 4 stages,
//     8 B-loads in flight/wave.
//     (2) XCD-affine swizzle bx=(bx&7)*128+(bx>>3): XCD x gets all 128 blocks
//     of batch x -> its 1 MB WhT slice stays L2-resident (was: every XCD
//     pulled every batch's slice through L3).
// grid 1024: b(8) x itile(128,16i); 512 thr / 8 waves; LDS 64 KB.
// ---------------------------------------------------------------------------
__global__ __launch_bounds__(512, 4) void k_pv(
    const float* __restrict__ attf, const unsigned short* __restrict__ WhT,
    const float* __restrict__ h, float* __restrict__ out) {
  __shared__ __align__(16) unsigned short satt[16 * 2048];  // 64 KB
  int bx = blockIdx.x;
  bx = (bx & 7) * 128 + (bx >> 3);   // XCD-affine remap (bijective on [0,1024))
  int b = bx >> 7;
  int i0 = (bx & 127) * 16;
  int tid = threadIdx.x;

  // ---- stage A-tile: 16 rows x 2048 fp32 -> bf16 swizzled LDS ----
  {
    int r = tid >> 5;                 // 0..15 (32 threads per row)
    int m0 = (tid & 31) * 8;          // 8 elems per thread per chunk
    const float* arow = attf + ((size_t)(b * NN + i0 + r)) * NN;
    unsigned short* srow = satt + r * 2048;
    int swz = r * 8;
#pragma unroll
    for (int c = 0; c < 8; ++c) {
      int j = c * 256 + m0;           // 8-aligned
      float4 p0 = *(const float4*)(arow + j);
      float4 p1 = *(const float4*)(arow + j + 4);
      *(bf16x8*)(srow + (j ^ swz)) = cvt8(p0, p1);
    }
  }
  __syncthreads();

  // ---- GEMM 16i x 256f x 2048j, 4-deep pipelined + fused epilogue ----
  int wave = tid >> 6, lane = tid & 63;
  int fW = wave * 32;
  int l15 = lane & 15, q8 = (lane >> 4) * 8;
  const unsigned short* WTb = WhT + (size_t)b * NF * NN;
  const unsigned short* aRow = satt + l15 * 2048;
  int swzA = l15 * 8;
  const unsigned short* bp = WTb + (size_t)(fW + l15) * NN + q8;  // B row base
  const size_t ROW16 = (size_t)16 * NN;

  f32x4 acc[2];
  acc[0] = (f32x4){0.f, 0.f, 0.f, 0.f};
  acc[1] = (f32x4){0.f, 0.f, 0.f, 0.f};

  // prologue: B for steps 0..3 (8 loads in flight), A for step 0
  bf16x8 bb0[2], bb1[2], bb2[2], bb3[2];
  bb0[0] = *(const bf16x8*)(bp + 0);    bb0[1] = *(const bf16x8*)(bp + ROW16 + 0);
  bb1[0] = *(const bf16x8*)(bp + 32);   bb1[1] = *(const bf16x8*)(bp + ROW16 + 32);
  bb2[0] = *(const bf16x8*)(bp + 64);   bb2[1] = *(const bf16x8*)(bp + ROW16 + 64);
  bb3[0] = *(const bf16x8*)(bp + 96);   bb3[1] = *(const bf16x8*)(bp + ROW16 + 96);
  bf16x8 a0 = *(const bf16x8*)(aRow + ((0 + q8) ^ swzA));
  bf16x8 a1, a2, a3;

  for (int kk = 0; kk < NN; kk += 128) {
    // stage 0: compute kk (bb0, a0); prefetch A(kk+32), B(kk+128)
    a1 = *(const bf16x8*)(aRow + (((kk + 32) + q8) ^ swzA));
    acc[0] = __builtin_amdgcn_mfma_f32_16x16x32_bf16(a0, bb0[0], acc[0], 0, 0, 0);
    acc[1] = __builtin_amdgcn_mfma_f32_16x16x32_bf16(a0, bb0[1], acc[1], 0, 0, 0);
    {
      int kp = kk + 128;
      if (kp < NN) {
        bb0[0] = *(const bf16x8*)(bp + kp);
        bb0[1] = *(const bf16x8*)(bp + ROW16 + kp);
      }
    }
    // stage 1: compute kk+32 (bb1, a1); prefetch A(kk+64), B(kk+160)
    a2 = *(const bf16x8*)(aRow + (((kk + 64) + q8) ^ swzA));
    acc[0] = __builtin_amdgcn_mfma_f32_16x16x32_bf16(a1, bb1[0], acc[0], 0, 0, 0);
    acc[1] = __builtin_amdgcn_mfma_f32_16x16x32_bf16(a1, bb1[1], acc[1], 0, 0, 0);
    {
      int kp = kk + 160;
      if (kp < NN) {
        bb1[0] = *(const bf16x8*)(bp + kp);
        bb1[1] = *(const bf16x8*)(bp + ROW16 + kp);
      }
    }
    // stage 2: compute kk+64 (bb2, a2); prefetch A(kk+96), B(kk+192)
    a3 = *(const bf16x8*)(aRow + (((kk + 96) + q8) ^ swzA));
    acc[0] = __builtin_amdgcn_mfma_f32_16x16x32_bf16(a2, bb2[0], acc[0], 0, 0, 0);
    acc[1] = __builtin_amdgcn_mfma_f32_16x16x32_bf16(a2, bb2[1], acc[1], 0, 0, 0);
    {
      int kp = kk + 192;
      if (kp < NN) {
        bb2[0] = *(const bf16x8*)(bp + kp);
        bb2[1] = *(const bf16x8*)(bp + ROW16 + kp);
      }
    }
    // stage 3: compute kk+96 (bb3, a3); prefetch A(kk+128), B(kk+224)
    {
      int ka = kk + 128;
      if (ka < NN) a0 = *(const bf16x8*)(aRow + ((ka + q8) ^ swzA));
    }
    acc[0] = __builtin_amdgcn_mfma_f32_16x16x32_bf16(a3, bb3[0], acc[0], 0, 0, 0);
    acc[1] = __builtin_amdgcn_mfma_f32_16x16x32_bf16(a3, bb3[1], acc[1], 0, 0, 0);
    {
      int kp = kk + 224;
      if (kp < NN) {
        bb3[0] = *(const bf16x8*)(bp + kp);
        bb3[1] = *(const bf16x8*)(bp + ROW16 + kp);
      }
    }
  }

  int q4 = (lane >> 4) * 4;
#pragma unroll
  for (int nt = 0; nt < 2; ++nt)
#pragma unroll
    for (int r = 0; r < 4; ++r) {
      int i = i0 + q4 + r;
      int f = fW + nt * 16 + l15;
      size_t idx = ((size_t)(b * NN + i)) * NF + f;
      float hp = acc[nt][r];
      float el = hp > 0.f ? hp : expm1f(hp);
      out[idx] = h[idx] + el;
    }
}

// ---------------------------------------------------------------------------
extern "C" void kernel_launch(void* const* d_in, const int* in_sizes, int n_in,
                              void* d_out, int out_size, void* d_ws, size_t ws_size,
                              hipStream_t stream) {
  // identify inputs by element count (all four are distinct)
  const float* h = nullptr; const int* adj = nullptr;
  const float* W = nullptr; const float* a = nullptr;
  for (int i = 0; i < n_in; ++i) {
    int s = in_sizes[i];
    if (s == NB * NN * NF) h = (const float*)d_in[i];
    else if (s == NB * NN * NN) adj = (const int*)d_in[i];
    else if (s == NF * NF) W = (const float*)d_in[i];
    else if (s == 2 * NF) a = (const float*)d_in[i];
  }

  float* out = (float*)d_out;                              // [8,2048,256] fp32
  float* att = out + (size_t)NB * NN * NF;                 // [8,2048,2048] fp32

  // ws footprint ~8.26 MB (proven safe)
  char* ws = (char*)d_ws;
  unsigned short* WhT = (unsigned short*)ws;               // 8 MB [8][256][2048] bf16
  unsigned short* WTr = (unsigned short*)(ws + 8388608);   // 128 KB [256][256] bf16
  float* u   = (float*)(ws + 8388608 + 131072);            // 1 KB
  float* v   = u + 256;                                    // 1 KB
  float* Wh1 = v + 256;                                    // 64 KB
  float* Wh2 = Wh1 + NB * NN;                              // 64 KB

  k_prep<<<257, 256, 0, stream>>>(W, a, WTr, u, v);
  k_wht<<<512, 256, 0, stream>>>(h, WTr, WhT);
  k_proj<<<NB * NN / 4, 256, 0, stream>>>(h, u, v, Wh1, Wh2);
  k_soft<<<NB * NN / 4, 256, 0, stream>>>(adj, Wh1, Wh2, att);
  k_pv<<<NB * 128, 512, 0, stream>>>(att, WhT, h, out);
}